// Round 10
// baseline (243.818 us; speedup 1.0000x reference)
//
#include <hip/hip_runtime.h>
#include <hip/hip_bf16.h>

// ---------------------------------------------------------------------------
// Fused self-attention, B=8 N=4096 D=256, f32 in/out, bf16 MFMA internally.
// ws: Qs bf16 [B*N][256] @0       (pre-scaled by log2e/16)
//     Kb bf16 [B*N][256] @16MB
//     VT bf16 [B][256][N] @32MB   (columns permuted per 16-block: 4-7 <-> 8-11)
// Attn: 512-thread blocks = 4 q-groups x 2 kv-halves; in-block LDS merge.
// R10: R9 minus the buggy permlane32_swap (back to __shfl_xor for cross-half
// reduce); keeps setprio + exp/pack<->PV interleave. Isolates scheduling A/B.
// ---------------------------------------------------------------------------

typedef __attribute__((ext_vector_type(8))) short short8;    // 8 bf16
typedef __attribute__((ext_vector_type(4))) float f32x4;
typedef __attribute__((ext_vector_type(16))) float f32x16;

#define MFMA16(A, B, C) __builtin_amdgcn_mfma_f32_16x16x32_bf16(A, B, C, 0, 0, 0)
#define MFMA32(A, B, C) __builtin_amdgcn_mfma_f32_32x32x16_bf16(A, B, C, 0, 0, 0)

__device__ __forceinline__ unsigned short f2bf(float f) {
  union { float f; unsigned u; } v; v.f = f;
  unsigned r = v.u + 0x7FFFu + ((v.u >> 16) & 1u);   // RNE
  return (unsigned short)(r >> 16);
}

__device__ __forceinline__ ushort4 pack4(float4 v) {
  ushort4 r;
  r.x = f2bf(v.x); r.y = f2bf(v.y); r.z = f2bf(v.z); r.w = f2bf(v.w);
  return r;
}

__device__ __forceinline__ unsigned packbf2(float a, float b) {
  union { __hip_bfloat162 b2; unsigned u; } cv;
  cv.b2 = __float22bfloat162_rn(make_float2(a, b));
  return cv.u;
}

__device__ __forceinline__ void gload_lds16(const void* g, void* l) {
  __builtin_amdgcn_global_load_lds(
      (const __attribute__((address_space(1))) void*)g,
      (__attribute__((address_space(3))) void*)l, 16, 0, 0);
}

// --------------------------- Projection GEMM (R3/R4-verified) -------------
template <int MODE>
__global__ __launch_bounds__(256)
void proj_kernel(const float* __restrict__ A, const float* __restrict__ Bm,
                 const float* __restrict__ bias,
                 unsigned short* __restrict__ Qs, unsigned short* __restrict__ Kb,
                 unsigned short* __restrict__ VT) {
  __shared__ __align__(16) unsigned short as_[2][128 * 64];
  __shared__ __align__(16) unsigned short bs_[2][128 * 64];

  const int tid = threadIdx.x;
  const int wid = tid >> 6, lane = tid & 63, l15 = lane & 15, lhi = lane >> 4;
  int m0, n0;
  if (MODE == 0) { m0 = blockIdx.y * 128; n0 = blockIdx.x * 128; }
  else           { m0 = blockIdx.x * 128; n0 = blockIdx.y * 128; }
  const float* Arow = A + (size_t)m0 * 256;
  const float* Brow = Bm + (size_t)n0 * 256;

  const int srow = tid >> 4;
  const int c4 = tid & 15;
  float4 ra[8], rb[8];

  auto loadslice = [&](int kc) {
#pragma unroll
    for (int i = 0; i < 8; ++i) {
      int row = i * 16 + srow;
      ra[i] = *(const float4*)(Arow + (size_t)row * 256 + kc * 64 + c4 * 4);
      rb[i] = *(const float4*)(Brow + (size_t)row * 256 + kc * 64 + c4 * 4);
    }
  };
  auto writeslice = [&](int buf) {
#pragma unroll
    for (int i = 0; i < 8; ++i) {
      int row = i * 16 + srow;
      int g = c4 >> 1, half = c4 & 1;
      int off = row * 64 + ((g ^ (row & 7)) << 3) + half * 4;
      *(ushort4*)&as_[buf][off] = pack4(ra[i]);
      *(ushort4*)&bs_[buf][off] = pack4(rb[i]);
    }
  };

  f32x4 acc[2][8];
#pragma unroll
  for (int mt = 0; mt < 2; ++mt)
#pragma unroll
    for (int nt = 0; nt < 8; ++nt) acc[mt][nt] = (f32x4){0.f, 0.f, 0.f, 0.f};

  loadslice(0);
  writeslice(0);
  int cur = 0;
  for (int kc = 0; kc < 4; ++kc) {
    __syncthreads();
    if (kc < 3) loadslice(kc + 1);
#pragma unroll
    for (int ks = 0; ks < 2; ++ks) {
      short8 af[2];
#pragma unroll
      for (int mt = 0; mt < 2; ++mt) {
        int row = wid * 32 + mt * 16 + l15;
        int g = ks * 4 + lhi;
        af[mt] = *(const short8*)&as_[cur][row * 64 + ((g ^ (row & 7)) << 3)];
      }
#pragma unroll
      for (int nt = 0; nt < 8; ++nt) {
        int row = nt * 16 + l15;
        int g = ks * 4 + lhi;
        short8 bf = *(const short8*)&bs_[cur][row * 64 + ((g ^ (row & 7)) << 3)];
        acc[0][nt] = MFMA16(af[0], bf, acc[0][nt]);
        acc[1][nt] = MFMA16(af[1], bf, acc[1][nt]);
      }
    }
    if (kc < 3) writeslice(cur ^ 1);
    cur ^= 1;
  }

  const float QSC = 0.0901684400555602f;  // log2(e)/16
#pragma unroll
  for (int nt = 0; nt < 8; ++nt) {
    if (MODE == 0) {
      int e = n0 + nt * 16 + l15;
      float bv = bias[e];
#pragma unroll
      for (int mt = 0; mt < 2; ++mt)
#pragma unroll
        for (int r = 0; r < 4; ++r) {
          int tok = m0 + wid * 32 + mt * 16 + lhi * 4 + r;
          float val = acc[mt][nt][r] + bv;
          if (e < 256) Qs[(size_t)tok * 256 + e] = f2bf(val * QSC);
          else         Kb[(size_t)tok * 256 + (e - 256)] = f2bf(val);
        }
    } else {
      int tok = n0 + nt * 16 + l15;
      int bb = tok >> 12, n = tok & 4095;
      // column involution within each 16-block: quads 1<->2, so VT' slot
      // order matches the native P-fragment kv order (crow8) in attn.
      int t4 = n & 15;
      int flip = ((t4 >> 2) ^ (t4 >> 3)) & 1;
      int n2 = (n & ~15) | (t4 ^ (flip ? 12 : 0));
#pragma unroll
      for (int mt = 0; mt < 2; ++mt)
#pragma unroll
        for (int r = 0; r < 4; ++r) {
          int d = m0 + wid * 32 + mt * 16 + lhi * 4 + r;
          float val = acc[mt][nt][r] + bias[512 + d];
          VT[(size_t)bb * (256 * 4096) + (size_t)d * 4096 + n2] = f2bf(val);
        }
    }
  }
}

// --------------------------- Flash attention ------------------------------
// Grid 256 = 8 batch * 32 q-blocks, 512 threads = 8 waves:
//   wave = (hv = wid>>2 kv-half) x (qg = wid&3 q-group of 32 rows).
// Swapped QK^T (A=K_lds, B=Q_regs): lane owns q=lane&31 for S/softmax;
// acco rows are q' = crow(r,h) -> per-row scales transported via __shfl.
// KVB=32, double-buffered per half; in-block LDS merge of the two halves.
__global__ __launch_bounds__(512, 2)
void attn_kernel(const unsigned short* __restrict__ Qs,
                 const unsigned short* __restrict__ Kb,
                 const unsigned short* __restrict__ VT,
                 float* __restrict__ out) {
  // [half][buf][ K 8192 shorts | V 8192 shorts ] = 128KB
  __shared__ __align__(16) unsigned short lds_kv[2][2][16384];
  __shared__ float2 lds_ml[8][32];   // 2KB

  const int tid = threadIdx.x;
  const int wid = tid >> 6, lane = tid & 63, l31 = lane & 31, h = lane >> 5;
  const int hv = wid >> 2;           // kv half
  const int qg = wid & 3;            // q group
  const int tid_h = tid & 255;       // thread within half
  const int blk = blockIdx.x;
  const int b = blk & 7;
  const int qblk = blk >> 3;         // 0..31
  const int q0 = qblk * 128 + qg * 32;

  // Q B-frags: lane holds q = l31, k = ks*16 + h*8 + e
  const unsigned short* qp = Qs + ((size_t)b * 4096 + q0 + l31) * 256 + h * 8;
  short8 qf[16];
#pragma unroll
  for (int ks = 0; ks < 16; ++ks) qf[ks] = *(const short8*)(qp + ks * 16);

  f32x16 acco[8];
#pragma unroll
  for (int dt = 0; dt < 8; ++dt)
#pragma unroll
    for (int j = 0; j < 16; ++j) acco[dt][j] = 0.f;
  float m = -1e30f, lsum = 0.f;

  const unsigned short* kbase = Kb + (size_t)b * 4096 * 256;
  const unsigned short* vtb   = VT + (size_t)b * 256 * 4096;

  auto stage = [&](int it, int buf) {
    const int kv0 = hv * 2048 + it * 32;
    unsigned short* kbuf = &lds_kv[hv][buf][0];
    unsigned short* vbuf = &lds_kv[hv][buf][8192];
    const unsigned short* ksrc = kbase + (size_t)kv0 * 256;
#pragma unroll
    for (int i = 0; i < 4; ++i) {
      int g = i * 256 + tid_h;              // K granule: 32 rows x 32
      int row = g >> 5, cp = g & 31;
      int sg = (row << 5) | (cp ^ (row & 7));
      gload_lds16(ksrc + sg * 8, kbuf + (i * 256 + (qg << 6)) * 8);
    }
#pragma unroll
    for (int i = 0; i < 4; ++i) {
      int g = i * 256 + tid_h;              // V granule: 256 rows x 4
      int d = g >> 2, cp = g & 3;
      int sc = cp ^ ((d >> 1) & 3);         // sigma(d)=(d>>1)&3
      gload_lds16(vtb + (size_t)d * 4096 + kv0 + sc * 8,
                  vbuf + (i * 256 + (qg << 6)) * 8);
    }
  };

  stage(0, 0);
  int cur = 0;
  for (int it = 0; it < 64; ++it) {
    __syncthreads();   // drains own gloads; prev readers of buf cur^1 done
    if (it < 63) stage(it + 1, cur ^ 1);
    const unsigned short* kb = &lds_kv[hv][cur][0];
    const unsigned short* vb = &lds_kv[hv][cur][8192];

    // ---- S^T = K·Q^T: lane holds col q=l31, rows kv=crow(r,h) ----
    f32x16 s0;
#pragma unroll
    for (int j = 0; j < 16; ++j) s0[j] = 0.f;
    __builtin_amdgcn_s_setprio(1);
#pragma unroll
    for (int ks = 0; ks < 16; ++ks) {
      const short8 kf =
          *(const short8*)&kb[l31 * 256 + (((2 * ks + h) ^ (l31 & 7)) << 3)];
      s0 = MFMA32(kf, qf[ks], s0);
    }
    __builtin_amdgcn_s_setprio(0);

    // ---- in-register online softmax for q = l31 ----
    float mx = s0[0];
#pragma unroll
    for (int r = 1; r < 16; ++r) mx = fmaxf(mx, s0[r]);
    mx = fmaxf(mx, __shfl_xor(mx, 32));           // cross-half (R8-verified)
    const float mo = m;
    const float mn = (mx > mo + 4.f) ? mx : mo;   // defer-max THR=4
    const float al = __builtin_amdgcn_exp2f(mo - mn);
    m = mn;
    if (__any(mn != mo)) {
      // acco rows are q' = crow(r,h): transport per-row scale via bpermute
      float alq[16];
#pragma unroll
      for (int r = 0; r < 16; ++r)
        alq[r] = __shfl(al, (r & 3) + 8 * (r >> 2) + 4 * h, 64);
#pragma unroll
      for (int dt = 0; dt < 8; ++dt)
#pragma unroll
        for (int r = 0; r < 16; ++r) acco[dt][r] *= alq[r];
    }

    // ---- P = exp2(S - mn); pack + PV interleaved (TRANS || matrix pipe) ----
#pragma unroll
    for (int r = 0; r < 8; ++r) s0[r] = __builtin_amdgcn_exp2f(s0[r] - mn);
    short8 pf0;
    {
      union { unsigned u[4]; short8 v; } a0;
#pragma unroll
      for (int k2 = 0; k2 < 4; ++k2)
        a0.u[k2] = packbf2(s0[2 * k2], s0[2 * k2 + 1]);
      pf0 = a0.v;
    }
    __builtin_amdgcn_s_setprio(1);
#pragma unroll
    for (int dt = 0; dt < 8; ++dt) {
      const int d = dt * 32 + l31;
      const short8 vf =
          *(const short8*)&vb[d * 32 + ((h ^ ((l31 >> 1) & 3)) << 3)];
      acco[dt] = MFMA32(pf0, vf, acco[dt]);
    }
    __builtin_amdgcn_s_setprio(0);
#pragma unroll
    for (int r = 8; r < 16; ++r) s0[r] = __builtin_amdgcn_exp2f(s0[r] - mn);
    short8 pf1;
    {
      union { unsigned u[4]; short8 v; } a1;
#pragma unroll
      for (int k2 = 0; k2 < 4; ++k2)
        a1.u[k2] = packbf2(s0[8 + 2 * k2], s0[9 + 2 * k2]);
      pf1 = a1.v;
    }
    __builtin_amdgcn_s_setprio(1);
#pragma unroll
    for (int dt = 0; dt < 8; ++dt) {
      const int d = dt * 32 + l31;
      const short8 vf =
          *(const short8*)&vb[d * 32 + (((2 + h) ^ ((l31 >> 1) & 3)) << 3)];
      acco[dt] = MFMA32(pf1, vf, acco[dt]);
    }
    __builtin_amdgcn_s_setprio(0);

    float rs = 0.f;
#pragma unroll
    for (int r = 0; r < 16; ++r) rs += s0[r];
    rs += __shfl_xor(rs, 32);                     // cross-half (R8-verified)
    lsum = lsum * al + rs;
    cur ^= 1;
  }

  // ---- in-block merge of the two kv halves (reuse tile LDS) ----
  __syncthreads();   // last compute done; safe to alias tiles
  if (lane < 32) lds_ml[wid][lane] = make_float2(m, lsum);
  float* o_base = (float*)&lds_kv[0][0][0];
  if (hv == 1) {
    float* o = o_base + qg * 8192;     // [32 q'][256 d] f32
#pragma unroll
    for (int dt = 0; dt < 8; ++dt)
#pragma unroll
      for (int r = 0; r < 16; ++r) {
        int qp2 = (r & 3) + 8 * (r >> 2) + 4 * h;
        o[qp2 * 256 + dt * 32 + l31] = acco[dt][r];
      }
  }
  __syncthreads();
  if (hv == 0) {
    float* o = o_base + qg * 8192;
    float* orow = out + ((size_t)b * 4096 + q0) * 256;
#pragma unroll
    for (int r = 0; r < 16; ++r) {
      int qp2 = (r & 3) + 8 * (r >> 2) + 4 * h;
      float2 s_own = lds_ml[wid][qp2];
      float2 s_par = lds_ml[wid + 4][qp2];
      float mM = fmaxf(s_own.x, s_par.x);
      float w0 = __builtin_amdgcn_exp2f(s_own.x - mM);
      float w1 = __builtin_amdgcn_exp2f(s_par.x - mM);
      float inv = 1.f / (w0 * s_own.y + w1 * s_par.y);
#pragma unroll
      for (int dt = 0; dt < 8; ++dt) {
        float val = (acco[dt][r] * w0 + o[qp2 * 256 + dt * 32 + l31] * w1) * inv;
        orow[(size_t)qp2 * 256 + dt * 32 + l31] = val;
      }
    }
  }
}

// ---------------------------------------------------------------------------
extern "C" void kernel_launch(void* const* d_in, const int* in_sizes, int n_in,
                              void* d_out, int out_size, void* d_ws, size_t ws_size,
                              hipStream_t stream) {
  const float* x    = (const float*)d_in[0];   // [8,4096,256]
  const float* W    = (const float*)d_in[1];   // [768,256]
  const float* bias = (const float*)d_in[2];   // [768]
  float* out = (float*)d_out;                  // [8,4096,256] f32

  char* ws = (char*)d_ws;
  unsigned short* Qs = (unsigned short*)(ws);
  unsigned short* Kb = (unsigned short*)(ws + (size_t)16 * 1024 * 1024);
  unsigned short* VT = (unsigned short*)(ws + (size_t)32 * 1024 * 1024);

  proj_kernel<0><<<dim3(4, 256), 256, 0, stream>>>(x, W, bias, Qs, Kb, VT);
  proj_kernel<1><<<dim3(2, 256), 256, 0, stream>>>(W + 512 * 256, x, bias, Qs, Kb, VT);
  attn_kernel<<<256, 512, 0, stream>>>(Qs, Kb, VT, out);
}

// Round 11
// 243.676 us; speedup vs baseline: 1.0006x; 1.0006x over previous
//
#include <hip/hip_runtime.h>
#include <hip/hip_bf16.h>

// ---------------------------------------------------------------------------
// Fused self-attention, B=8 N=4096 D=256, f32 in/out, bf16 MFMA internally.
// ws: Qs bf16 [B*N][256] @0       (pre-scaled by log2e/16)
//     Kb bf16 [B*N][256] @16MB
//     VT bf16 [B][256][N] @32MB   (columns permuted per 16-block: 4-7 <-> 8-11)
//     O1 f32  [B*N][256]  @48MB   (kv-half-1 unnorm partial; half-0 -> out)
//     ML f32x2 [2][B*N]   @80MB
// R11: kv-halves as SEPARATE 256-thread blocks (independent barriers ->
// anti-phase overlap on the CU), global merge pass. Falls back to the R10
// fused 512-thread kernel when ws_size < 81MB.
// ---------------------------------------------------------------------------

typedef __attribute__((ext_vector_type(8))) short short8;    // 8 bf16
typedef __attribute__((ext_vector_type(4))) float f32x4;
typedef __attribute__((ext_vector_type(16))) float f32x16;

#define MFMA16(A, B, C) __builtin_amdgcn_mfma_f32_16x16x32_bf16(A, B, C, 0, 0, 0)
#define MFMA32(A, B, C) __builtin_amdgcn_mfma_f32_32x32x16_bf16(A, B, C, 0, 0, 0)

__device__ __forceinline__ unsigned short f2bf(float f) {
  union { float f; unsigned u; } v; v.f = f;
  unsigned r = v.u + 0x7FFFu + ((v.u >> 16) & 1u);   // RNE
  return (unsigned short)(r >> 16);
}

__device__ __forceinline__ ushort4 pack4(float4 v) {
  ushort4 r;
  r.x = f2bf(v.x); r.y = f2bf(v.y); r.z = f2bf(v.z); r.w = f2bf(v.w);
  return r;
}

__device__ __forceinline__ unsigned packbf2(float a, float b) {
  union { __hip_bfloat162 b2; unsigned u; } cv;
  cv.b2 = __float22bfloat162_rn(make_float2(a, b));
  return cv.u;
}

__device__ __forceinline__ void gload_lds16(const void* g, void* l) {
  __builtin_amdgcn_global_load_lds(
      (const __attribute__((address_space(1))) void*)g,
      (__attribute__((address_space(3))) void*)l, 16, 0, 0);
}

// --------------------------- Projection GEMM (R3/R4-verified) -------------
template <int MODE>
__global__ __launch_bounds__(256)
void proj_kernel(const float* __restrict__ A, const float* __restrict__ Bm,
                 const float* __restrict__ bias,
                 unsigned short* __restrict__ Qs, unsigned short* __restrict__ Kb,
                 unsigned short* __restrict__ VT) {
  __shared__ __align__(16) unsigned short as_[2][128 * 64];
  __shared__ __align__(16) unsigned short bs_[2][128 * 64];

  const int tid = threadIdx.x;
  const int wid = tid >> 6, lane = tid & 63, l15 = lane & 15, lhi = lane >> 4;
  int m0, n0;
  if (MODE == 0) { m0 = blockIdx.y * 128; n0 = blockIdx.x * 128; }
  else           { m0 = blockIdx.x * 128; n0 = blockIdx.y * 128; }
  const float* Arow = A + (size_t)m0 * 256;
  const float* Brow = Bm + (size_t)n0 * 256;

  const int srow = tid >> 4;
  const int c4 = tid & 15;
  float4 ra[8], rb[8];

  auto loadslice = [&](int kc) {
#pragma unroll
    for (int i = 0; i < 8; ++i) {
      int row = i * 16 + srow;
      ra[i] = *(const float4*)(Arow + (size_t)row * 256 + kc * 64 + c4 * 4);
      rb[i] = *(const float4*)(Brow + (size_t)row * 256 + kc * 64 + c4 * 4);
    }
  };
  auto writeslice = [&](int buf) {
#pragma unroll
    for (int i = 0; i < 8; ++i) {
      int row = i * 16 + srow;
      int g = c4 >> 1, half = c4 & 1;
      int off = row * 64 + ((g ^ (row & 7)) << 3) + half * 4;
      *(ushort4*)&as_[buf][off] = pack4(ra[i]);
      *(ushort4*)&bs_[buf][off] = pack4(rb[i]);
    }
  };

  f32x4 acc[2][8];
#pragma unroll
  for (int mt = 0; mt < 2; ++mt)
#pragma unroll
    for (int nt = 0; nt < 8; ++nt) acc[mt][nt] = (f32x4){0.f, 0.f, 0.f, 0.f};

  loadslice(0);
  writeslice(0);
  int cur = 0;
  for (int kc = 0; kc < 4; ++kc) {
    __syncthreads();
    if (kc < 3) loadslice(kc + 1);
#pragma unroll
    for (int ks = 0; ks < 2; ++ks) {
      short8 af[2];
#pragma unroll
      for (int mt = 0; mt < 2; ++mt) {
        int row = wid * 32 + mt * 16 + l15;
        int g = ks * 4 + lhi;
        af[mt] = *(const short8*)&as_[cur][row * 64 + ((g ^ (row & 7)) << 3)];
      }
#pragma unroll
      for (int nt = 0; nt < 8; ++nt) {
        int row = nt * 16 + l15;
        int g = ks * 4 + lhi;
        short8 bf = *(const short8*)&bs_[cur][row * 64 + ((g ^ (row & 7)) << 3)];
        acc[0][nt] = MFMA16(af[0], bf, acc[0][nt]);
        acc[1][nt] = MFMA16(af[1], bf, acc[1][nt]);
      }
    }
    if (kc < 3) writeslice(cur ^ 1);
    cur ^= 1;
  }

  const float QSC = 0.0901684400555602f;  // log2(e)/16
#pragma unroll
  for (int nt = 0; nt < 8; ++nt) {
    if (MODE == 0) {
      int e = n0 + nt * 16 + l15;
      float bv = bias[e];
#pragma unroll
      for (int mt = 0; mt < 2; ++mt)
#pragma unroll
        for (int r = 0; r < 4; ++r) {
          int tok = m0 + wid * 32 + mt * 16 + lhi * 4 + r;
          float val = acc[mt][nt][r] + bv;
          if (e < 256) Qs[(size_t)tok * 256 + e] = f2bf(val * QSC);
          else         Kb[(size_t)tok * 256 + (e - 256)] = f2bf(val);
        }
    } else {
      int tok = n0 + nt * 16 + l15;
      int bb = tok >> 12, n = tok & 4095;
      int t4 = n & 15;
      int flip = ((t4 >> 2) ^ (t4 >> 3)) & 1;
      int n2 = (n & ~15) | (t4 ^ (flip ? 12 : 0));
#pragma unroll
      for (int mt = 0; mt < 2; ++mt)
#pragma unroll
        for (int r = 0; r < 4; ++r) {
          int d = m0 + wid * 32 + mt * 16 + lhi * 4 + r;
          float val = acc[mt][nt][r] + bias[512 + d];
          VT[(size_t)bb * (256 * 4096) + (size_t)d * 4096 + n2] = f2bf(val);
        }
    }
  }
}

// --------------------------- Flash attention, split-K blocks --------------
// Grid 512 = 8 batch * 2 kv-half * 32 q-blocks; 256 threads = 4 waves x 32 q.
// LDS 64KB (KVB=32, dbuf) -> 2 independent blocks/CU -> anti-phase overlap.
// Writes UNNORMALIZED partial O (half0 -> out, half1 -> O1) + (m,l) to ML.
__global__ __launch_bounds__(256, 2)
void attn_split(const unsigned short* __restrict__ Qs,
                const unsigned short* __restrict__ Kb,
                const unsigned short* __restrict__ VT,
                float* __restrict__ out, float* __restrict__ O1,
                float2* __restrict__ ML) {
  __shared__ __align__(16) unsigned short lds_kv[2][16384];  // 64KB

  const int tid = threadIdx.x;
  const int wid = tid >> 6, lane = tid & 63, l31 = lane & 31, h = lane >> 5;
  const int blk = blockIdx.x;
  const int b = blk & 7;
  const int hh = (blk >> 3) & 1;
  const int qblk = blk >> 4;           // 0..31
  const int q0 = qblk * 128 + wid * 32;

  const unsigned short* qp = Qs + ((size_t)b * 4096 + q0 + l31) * 256 + h * 8;
  short8 qf[16];
#pragma unroll
  for (int ks = 0; ks < 16; ++ks) qf[ks] = *(const short8*)(qp + ks * 16);

  f32x16 acco[8];
#pragma unroll
  for (int dt = 0; dt < 8; ++dt)
#pragma unroll
    for (int j = 0; j < 16; ++j) acco[dt][j] = 0.f;
  float m = -1e30f, lsum = 0.f;

  const unsigned short* kbase = Kb + (size_t)b * 4096 * 256;
  const unsigned short* vtb   = VT + (size_t)b * 256 * 4096;

  auto stage = [&](int it, int buf) {
    const int kv0 = hh * 2048 + it * 32;
    unsigned short* kbuf = &lds_kv[buf][0];
    unsigned short* vbuf = &lds_kv[buf][8192];
    const unsigned short* ksrc = kbase + (size_t)kv0 * 256;
#pragma unroll
    for (int i = 0; i < 4; ++i) {
      int g = i * 256 + tid;                // K granule: 32 rows x 32
      int row = g >> 5, cp = g & 31;
      int sg = (row << 5) | (cp ^ (row & 7));
      gload_lds16(ksrc + sg * 8, kbuf + (i * 256 + (wid << 6)) * 8);
    }
#pragma unroll
    for (int i = 0; i < 4; ++i) {
      int g = i * 256 + tid;                // V granule: 256 rows x 4
      int d = g >> 2, cp = g & 3;
      int sc = cp ^ ((d >> 1) & 3);         // sigma(d)=(d>>1)&3
      gload_lds16(vtb + (size_t)d * 4096 + kv0 + sc * 8,
                  vbuf + (i * 256 + (wid << 6)) * 8);
    }
  };

  stage(0, 0);
  int cur = 0;
  for (int it = 0; it < 64; ++it) {
    __syncthreads();
    if (it < 63) stage(it + 1, cur ^ 1);
    const unsigned short* kb = &lds_kv[cur][0];
    const unsigned short* vb = &lds_kv[cur][8192];

    f32x16 s0;
#pragma unroll
    for (int j = 0; j < 16; ++j) s0[j] = 0.f;
    __builtin_amdgcn_s_setprio(1);
#pragma unroll
    for (int ks = 0; ks < 16; ++ks) {
      const short8 kf =
          *(const short8*)&kb[l31 * 256 + (((2 * ks + h) ^ (l31 & 7)) << 3)];
      s0 = MFMA32(kf, qf[ks], s0);
    }
    __builtin_amdgcn_s_setprio(0);

    float mx = s0[0];
#pragma unroll
    for (int r = 1; r < 16; ++r) mx = fmaxf(mx, s0[r]);
    mx = fmaxf(mx, __shfl_xor(mx, 32));
    const float mo = m;
    const float mn = (mx > mo + 4.f) ? mx : mo;   // defer-max THR=4
    const float al = __builtin_amdgcn_exp2f(mo - mn);
    m = mn;
    if (__any(mn != mo)) {
      float alq[16];
#pragma unroll
      for (int r = 0; r < 16; ++r)
        alq[r] = __shfl(al, (r & 3) + 8 * (r >> 2) + 4 * h, 64);
#pragma unroll
      for (int dt = 0; dt < 8; ++dt)
#pragma unroll
        for (int r = 0; r < 16; ++r) acco[dt][r] *= alq[r];
    }

#pragma unroll
    for (int r = 0; r < 8; ++r) s0[r] = __builtin_amdgcn_exp2f(s0[r] - mn);
    short8 pf0;
    {
      union { unsigned u[4]; short8 v; } a0;
#pragma unroll
      for (int k2 = 0; k2 < 4; ++k2)
        a0.u[k2] = packbf2(s0[2 * k2], s0[2 * k2 + 1]);
      pf0 = a0.v;
    }
    __builtin_amdgcn_s_setprio(1);
#pragma unroll
    for (int dt = 0; dt < 8; ++dt) {
      const int d = dt * 32 + l31;
      const short8 vf =
          *(const short8*)&vb[d * 32 + ((h ^ ((l31 >> 1) & 3)) << 3)];
      acco[dt] = MFMA32(pf0, vf, acco[dt]);
    }
    __builtin_amdgcn_s_setprio(0);
#pragma unroll
    for (int r = 8; r < 16; ++r) s0[r] = __builtin_amdgcn_exp2f(s0[r] - mn);
    short8 pf1;
    {
      union { unsigned u[4]; short8 v; } a1;
#pragma unroll
      for (int k2 = 0; k2 < 4; ++k2)
        a1.u[k2] = packbf2(s0[8 + 2 * k2], s0[9 + 2 * k2]);
      pf1 = a1.v;
    }
    __builtin_amdgcn_s_setprio(1);
#pragma unroll
    for (int dt = 0; dt < 8; ++dt) {
      const int d = dt * 32 + l31;
      const short8 vf =
          *(const short8*)&vb[d * 32 + (((2 + h) ^ ((l31 >> 1) & 3)) << 3)];
      acco[dt] = MFMA32(pf1, vf, acco[dt]);
    }
    __builtin_amdgcn_s_setprio(0);

    float rs = 0.f;
#pragma unroll
    for (int r = 0; r < 16; ++r) rs += s0[r];
    rs += __shfl_xor(rs, 32);
    lsum = lsum * al + rs;
    cur ^= 1;
  }

  // store UNNORMALIZED partial + (m,l); merge kernel normalizes
  float* op = (hh ? O1 : out) + ((size_t)b * 4096 + q0) * 256;
#pragma unroll
  for (int dt = 0; dt < 8; ++dt)
#pragma unroll
    for (int r = 0; r < 16; ++r) {
      int qp2 = (r & 3) + 8 * (r >> 2) + 4 * h;
      op[(size_t)qp2 * 256 + dt * 32 + l31] = acco[dt][r];
    }
  if (lane < 32)
    ML[hh * 32768 + (size_t)b * 4096 + q0 + lane] = make_float2(m, lsum);
}

// --------------------------- Merge of the two kv halves -------------------
__global__ __launch_bounds__(256)
void merge_kernel(float* __restrict__ out, const float* __restrict__ O1,
                  const float2* __restrict__ ML) {
  const int i4 = blockIdx.x * 256 + threadIdx.x;   // float4 index
  const int row = i4 >> 6;                          // b*4096 + n
  const float2 s0 = ML[row], s1 = ML[32768 + row];
  const float mM = fmaxf(s0.x, s1.x);
  const float w0 = __builtin_amdgcn_exp2f(s0.x - mM);
  const float w1 = __builtin_amdgcn_exp2f(s1.x - mM);
  const float inv = 1.f / (w0 * s0.y + w1 * s1.y);
  const float4 a = ((const float4*)out)[i4];
  const float4 c = ((const float4*)O1)[i4];
  float4 r;
  r.x = (a.x * w0 + c.x * w1) * inv;
  r.y = (a.y * w0 + c.y * w1) * inv;
  r.z = (a.z * w0 + c.z * w1) * inv;
  r.w = (a.w * w0 + c.w * w1) * inv;
  ((float4*)out)[i4] = r;
}

// --------------------------- R10 fused fallback (ws too small) ------------
__global__ __launch_bounds__(512, 2)
void attn_fused(const unsigned short* __restrict__ Qs,
                const unsigned short* __restrict__ Kb,
                const unsigned short* __restrict__ VT,
                float* __restrict__ out) {
  __shared__ __align__(16) unsigned short lds_kv[2][2][16384];
  __shared__ float2 lds_ml[8][32];

  const int tid = threadIdx.x;
  const int wid = tid >> 6, lane = tid & 63, l31 = lane & 31, h = lane >> 5;
  const int hv = wid >> 2;
  const int qg = wid & 3;
  const int tid_h = tid & 255;
  const int blk = blockIdx.x;
  const int b = blk & 7;
  const int qblk = blk >> 3;
  const int q0 = qblk * 128 + qg * 32;

  const unsigned short* qp = Qs + ((size_t)b * 4096 + q0 + l31) * 256 + h * 8;
  short8 qf[16];
#pragma unroll
  for (int ks = 0; ks < 16; ++ks) qf[ks] = *(const short8*)(qp + ks * 16);

  f32x16 acco[8];
#pragma unroll
  for (int dt = 0; dt < 8; ++dt)
#pragma unroll
    for (int j = 0; j < 16; ++j) acco[dt][j] = 0.f;
  float m = -1e30f, lsum = 0.f;

  const unsigned short* kbase = Kb + (size_t)b * 4096 * 256;
  const unsigned short* vtb   = VT + (size_t)b * 256 * 4096;

  auto stage = [&](int it, int buf) {
    const int kv0 = hv * 2048 + it * 32;
    unsigned short* kbuf = &lds_kv[hv][buf][0];
    unsigned short* vbuf = &lds_kv[hv][buf][8192];
    const unsigned short* ksrc = kbase + (size_t)kv0 * 256;
#pragma unroll
    for (int i = 0; i < 4; ++i) {
      int g = i * 256 + tid_h;
      int row = g >> 5, cp = g & 31;
      int sg = (row << 5) | (cp ^ (row & 7));
      gload_lds16(ksrc + sg * 8, kbuf + (i * 256 + (qg << 6)) * 8);
    }
#pragma unroll
    for (int i = 0; i < 4; ++i) {
      int g = i * 256 + tid_h;
      int d = g >> 2, cp = g & 3;
      int sc = cp ^ ((d >> 1) & 3);
      gload_lds16(vtb + (size_t)d * 4096 + kv0 + sc * 8,
                  vbuf + (i * 256 + (qg << 6)) * 8);
    }
  };

  stage(0, 0);
  int cur = 0;
  for (int it = 0; it < 64; ++it) {
    __syncthreads();
    if (it < 63) stage(it + 1, cur ^ 1);
    const unsigned short* kb = &lds_kv[hv][cur][0];
    const unsigned short* vb = &lds_kv[hv][cur][8192];

    f32x16 s0;
#pragma unroll
    for (int j = 0; j < 16; ++j) s0[j] = 0.f;
#pragma unroll
    for (int ks = 0; ks < 16; ++ks) {
      const short8 kf =
          *(const short8*)&kb[l31 * 256 + (((2 * ks + h) ^ (l31 & 7)) << 3)];
      s0 = MFMA32(kf, qf[ks], s0);
    }

    float mx = s0[0];
#pragma unroll
    for (int r = 1; r < 16; ++r) mx = fmaxf(mx, s0[r]);
    mx = fmaxf(mx, __shfl_xor(mx, 32));
    const float mo = m;
    const float mn = (mx > mo + 4.f) ? mx : mo;
    const float al = __builtin_amdgcn_exp2f(mo - mn);
    m = mn;
    if (__any(mn != mo)) {
      float alq[16];
#pragma unroll
      for (int r = 0; r < 16; ++r)
        alq[r] = __shfl(al, (r & 3) + 8 * (r >> 2) + 4 * h, 64);
#pragma unroll
      for (int dt = 0; dt < 8; ++dt)
#pragma unroll
        for (int r = 0; r < 16; ++r) acco[dt][r] *= alq[r];
    }

    float rs = 0.f;
#pragma unroll
    for (int r = 0; r < 16; ++r) {
      s0[r] = __builtin_amdgcn_exp2f(s0[r] - mn);
      rs += s0[r];
    }
    rs += __shfl_xor(rs, 32);
    lsum = lsum * al + rs;

    short8 pf[2];
    {
      union { unsigned u[4]; short8 v; } a0, a1;
#pragma unroll
      for (int k2 = 0; k2 < 4; ++k2) {
        a0.u[k2] = packbf2(s0[2 * k2], s0[2 * k2 + 1]);
        a1.u[k2] = packbf2(s0[8 + 2 * k2], s0[9 + 2 * k2]);
      }
      pf[0] = a0.v; pf[1] = a1.v;
    }
#pragma unroll
    for (int ks = 0; ks < 2; ++ks) {
#pragma unroll
      for (int dt = 0; dt < 8; ++dt) {
        const int d = dt * 32 + l31;
        const short8 vf = *(const short8*)
            &vb[d * 32 + (((2 * ks + h) ^ ((l31 >> 1) & 3)) << 3)];
        acco[dt] = MFMA32(pf[ks], vf, acco[dt]);
      }
    }
    cur ^= 1;
  }

  __syncthreads();
  if (lane < 32) lds_ml[wid][lane] = make_float2(m, lsum);
  float* o_base = (float*)&lds_kv[0][0][0];
  if (hv == 1) {
    float* o = o_base + qg * 8192;
#pragma unroll
    for (int dt = 0; dt < 8; ++dt)
#pragma unroll
      for (int r = 0; r < 16; ++r) {
        int qp2 = (r & 3) + 8 * (r >> 2) + 4 * h;
        o[qp2 * 256 + dt * 32 + l31] = acco[dt][r];
      }
  }
  __syncthreads();
  if (hv == 0) {
    float* o = o_base + qg * 8192;
    float* orow = out + ((size_t)b * 4096 + q0) * 256;
#pragma unroll
    for (int r = 0; r < 16; ++r) {
      int qp2 = (r & 3) + 8 * (r >> 2) + 4 * h;
      float2 s_own = lds_ml[wid][qp2];
      float2 s_par = lds_ml[wid + 4][qp2];
      float mM = fmaxf(s_own.x, s_par.x);
      float w0 = __builtin_amdgcn_exp2f(s_own.x - mM);
      float w1 = __builtin_amdgcn_exp2f(s_par.x - mM);
      float inv = 1.f / (w0 * s_own.y + w1 * s_par.y);
#pragma unroll
      for (int dt = 0; dt < 8; ++dt) {
        float val = (acco[dt][r] * w0 + o[qp2 * 256 + dt * 32 + l31] * w1) * inv;
        orow[(size_t)qp2 * 256 + dt * 32 + l31] = val;
      }
    }
  }
}

// ---------------------------------------------------------------------------
extern "C" void kernel_launch(void* const* d_in, const int* in_sizes, int n_in,
                              void* d_out, int out_size, void* d_ws, size_t ws_size,
                              hipStream_t stream) {
  const float* x    = (const float*)d_in[0];   // [8,4096,256]
  const float* W    = (const float*)d_in[1];   // [768,256]
  const float* bias = (const float*)d_in[2];   // [768]
  float* out = (float*)d_out;                  // [8,4096,256] f32

  char* ws = (char*)d_ws;
  unsigned short* Qs = (unsigned short*)(ws);
  unsigned short* Kb = (unsigned short*)(ws + (size_t)16 * 1024 * 1024);
  unsigned short* VT = (unsigned short*)(ws + (size_t)32 * 1024 * 1024);
  float*          O1 = (float*)(ws + (size_t)48 * 1024 * 1024);     // 32MB
  float2*         ML = (float2*)(ws + (size_t)80 * 1024 * 1024);    // 512KB

  proj_kernel<0><<<dim3(4, 256), 256, 0, stream>>>(x, W, bias, Qs, Kb, VT);
  proj_kernel<1><<<dim3(2, 256), 256, 0, stream>>>(W + 512 * 256, x, bias, Qs, Kb, VT);

  const size_t NEED = (size_t)81 * 1024 * 1024;
  if (ws_size >= NEED) {
    attn_split<<<512, 256, 0, stream>>>(Qs, Kb, VT, out, O1, ML);
    merge_kernel<<<8192, 256, 0, stream>>>(out, O1, ML);
  } else {
    attn_fused<<<256, 512, 0, stream>>>(Qs, Kb, VT, out);
  }
}